// Round 12
// baseline (2135.733 us; speedup 1.0000x reference)
//
#include <hip/hip_runtime.h>

#define B_ 256
#define T_ 256
#define H_ 300
#define IN_ 16
#define NT_ 75          // gate tiles (1200/16)
#define KSR_ 10         // recurrent K slabs (300 -> 320)
#define HP_ 320         // padded h row stride (elements)
#define MEMB_ 8         // member blocks per group per layer
#define WPB_ 10         // waves per block (640 threads)
#define RS0_ 8          // ring-0 slots (h0), power of 2

typedef __attribute__((ext_vector_type(8))) short short8;
typedef __attribute__((ext_vector_type(4))) float f32x4;
typedef unsigned int uint32;

union S8U { short8 s; uint32 u[4]; };

__device__ __forceinline__ unsigned short f2bf(float f) {
    uint32 u = __float_as_uint(f);
    u = u + 0x7fffu + ((u >> 16) & 1u);   // RNE
    return (unsigned short)(u >> 16);
}
__device__ __forceinline__ float bf2f(unsigned short h) {
    return __uint_as_float(((uint32)h) << 16);
}
__device__ __forceinline__ float sigm(float x) {
    float e = __expf(-x);
    return __builtin_amdgcn_rcpf(1.f + e);
}
__device__ __forceinline__ float tanh_f(float x) {
    float xc = fminf(fmaxf(x, -15.f), 15.f);
    float e = __expf(2.f * xc);
    return (e - 1.f) * __builtin_amdgcn_rcpf(e + 1.f);
}

// IF$ (coherence-point) ops: sc0 sc1 bypass L1/L2 -> coherent across XCDs,
// zero cache-maintenance. Used ONLY for the per-step exchange.
__device__ __forceinline__ short8 ld16c(const void* p) {
    short8 r;
    asm volatile("global_load_dwordx4 %0, %1, off sc0 sc1"
                 : "=v"(r) : "v"(p));
    return r;
}
__device__ __forceinline__ void st2c(unsigned short* p, unsigned short v) {
    uint32 vv = v;
    asm volatile("global_store_short %0, %1, off sc0 sc1" :: "v"(p), "v"(vv) : "memory");
}
__device__ __forceinline__ void st4c(int* p, int v) {
    asm volatile("global_store_dword %0, %1, off sc0 sc1" :: "v"(p), "v"(v) : "memory");
}
__device__ __forceinline__ void vm0() {
    asm volatile("s_waitcnt vmcnt(0)" ::: "memory");
}
// wave-wide poll of two 75-entry flag arrays (2 coalesced loads each + ballot)
__device__ __forceinline__ void poll75x2(const int* fA, const int* fB,
                                         int ta, int tb, int lane) {
    const int* a0p = fA + lane;       const int* a1p = fA + 64 + lane;
    const int* b0p = fB + lane;       const int* b1p = fB + 64 + lane;
    int it = 0;
    for (;;) {
        int a0, a1, b0, b1;
        asm volatile("global_load_dword %0, %4, off sc0 sc1\n\t"
                     "global_load_dword %1, %5, off sc0 sc1\n\t"
                     "global_load_dword %2, %6, off sc0 sc1\n\t"
                     "global_load_dword %3, %7, off sc0 sc1\n\t"
                     "s_waitcnt vmcnt(0)"
                     : "=&v"(a0), "=&v"(a1), "=&v"(b0), "=&v"(b1)
                     : "v"(a0p), "v"(a1p), "v"(b0p), "v"(b1p) : "memory");
        unsigned long long bad = __ballot(a0 < ta) | (__ballot(a1 < ta) & 0x7ffull)
                               | __ballot(b0 < tb) | (__ballot(b1 < tb) & 0x7ffull);
        if (bad == 0) break;
        __builtin_amdgcn_s_sleep(1);
        if (++it > (1 << 22)) break;   // bailout: wrong > hung
    }
}

#define MF(w_, a_, acc_) acc_ = __builtin_amdgcn_mfma_f32_16x16x32_bf16(w_, a_, acc_, 0, 0, 0)

// ---------------------------------------------------------------------------
// Weight packing into bf16 MFMA A-fragments, gate rows permuted unit-major.
// ---------------------------------------------------------------------------
__device__ __forceinline__ void pack_one(int idx, const float* __restrict__ W,
                                         int K, int KS, uint32* __restrict__ dst)
{
    int lane = idx & 63, ts = idx >> 6;
    int slab = ts % KS, tile = ts / KS;
    int rp = tile * 16 + (lane & 15);
    int jj = rp >> 2, g = rp & 3;
    int r = g * H_ + jj;
    int kb = slab * 32 + (lane >> 4) * 8;
    #pragma unroll
    for (int p = 0; p < 4; ++p) {
        int k0 = kb + 2 * p, k1 = k0 + 1;
        float v0 = (k0 < K) ? W[(size_t)r * K + k0] : 0.f;
        float v1 = (k1 < K) ? W[(size_t)r * K + k1] : 0.f;
        dst[(size_t)idx * 4 + p] = (uint32)f2bf(v0) | ((uint32)f2bf(v1) << 16);
    }
}

__global__ void pack_kernel(const float* __restrict__ Wih0, const float* __restrict__ Whh0,
                            const float* __restrict__ bih0, const float* __restrict__ bhh0,
                            const float* __restrict__ Wih1, const float* __restrict__ Whh1,
                            const float* __restrict__ bih1, const float* __restrict__ bhh1,
                            uint32* __restrict__ wr0, uint32* __restrict__ wg0,
                            uint32* __restrict__ wr1, uint32* __restrict__ wg1,
                            float* __restrict__ b0p, float* __restrict__ b1p)
{
    const int C0 = NT_ * KSR_ * 64;   // 48000
    const int C1 = NT_ * 64;          // 4800
    int id = blockIdx.x * 256 + threadIdx.x;
    if (id < C0) pack_one(id, Whh0, H_, KSR_, wr0);
    else if (id < C0 + C1) pack_one(id - C0, Wih0, IN_, 1, wg0);
    else if (id < 2 * C0 + C1) pack_one(id - C0 - C1, Whh1, H_, KSR_, wr1);
    else if (id < 3 * C0 + C1) pack_one(id - 2 * C0 - C1, Wih1, H_, KSR_, wg1);
    else if (id < 3 * C0 + C1 + 1200) {
        int p = id - 3 * C0 - C1;
        int jj = p >> 2, g = p & 3, r = g * H_ + jj;
        b0p[p] = bih0[r] + bhh0[r];
    } else if (id < 3 * C0 + C1 + 2400) {
        int p = id - 3 * C0 - C1 - 1200;
        int jj = p >> 2, g = p & 3, r = g * H_ + jj;
        b1p[p] = bih1[r] + bhh1[r];
    }
}

// ---------------------------------------------------------------------------
// BOTH LSTM layers in one dispatch, software-pipelined: 256 blocks x 640.
// blocks 0..127: layer 0; 128..255: layer 1 (lagging 1 step).
// Per-wave epoch flags (75/group/layer) at IF$: producer = {ring st2c ->
// vmcnt0 -> lane0 flag st4c} -- NO publish barrier, NO atomics. Consumer:
// wave0 ballot-polls flags, posts LDS gate; other waves LDS-spin; each wave
// stages its slab IF$->LDS; ONE __syncthreads/step. Ring0 8-deep so L0
// never stalls on L1 jitter (back-pressure >= t-7).
// ---------------------------------------------------------------------------
__global__ __launch_bounds__(640) void lstm_dual(
    const float* __restrict__ x,
    const short8* __restrict__ wr0, const short8* __restrict__ wg0,
    const short8* __restrict__ wr1, const short8* __restrict__ wg1,
    const float* __restrict__ b0p, const float* __restrict__ b1p,
    unsigned short* __restrict__ h1rm,
    unsigned short* __restrict__ ring0, unsigned short* __restrict__ ring1,
    int* __restrict__ flags)
{
    __shared__ short8 wlds[WPB_ * KSR_ * 64];   // 100 KB: Whh tiles
    __shared__ short8 alds[KSR_ * 64];          // 10 KB: own-layer h state
    __shared__ short8 a0lds[KSR_ * 64];         // 10 KB: h0[t] (layer 1 only)
    __shared__ int gate;                        // step whose staging is released

    const int tid = threadIdx.x;
    const int wave = tid >> 6, lane = tid & 63;
    const int layer = (int)(blockIdx.x >> 7);
    const int lb = blockIdx.x & 127;
    const int g = lb & 15, member = lb >> 4;
    const int rawwt = member * WPB_ + wave;      // 0..79
    const bool act = rawwt < NT_;
    const int wtile = act ? rawwt : NT_ - 1;
    const int m = lane & 15, oct = lane >> 4;

    {   // one-time: weights -> LDS; zero own-state buffer (h[-1] = 0); gate=-1
        const short8* wsrc = (layer ? wr1 : wr0) + (size_t)member * (WPB_ * KSR_ * 64);
        for (int i = tid; i < WPB_ * KSR_ * 64; i += 640) wlds[i] = wsrc[i];
        short8 z = {0, 0, 0, 0, 0, 0, 0, 0};
        if (tid < KSR_ * 64) alds[tid] = z;
        if (tid == 0) gate = -1;
    }
    short8 wxv;
    if (layer == 0) wxv = wg0[(size_t)wtile * 64 + lane];
    const float* bp = layer ? b1p : b0p;
    const f32x4 b4 = *(const f32x4*)&bp[wtile * 16 + oct * 4];

    unsigned short* r0g = ring0 + (size_t)g * (RS0_ * 5120);
    unsigned short* r1g = ring1 + (size_t)g * (2 * 5120);
    int* f0 = flags + g * 128;            // layer-0 per-wave flags (75 used)
    int* f1 = flags + 2048 + g * 128;     // layer-1
    int* fown = (layer ? f1 : f0) + rawwt;

    const int jj = wtile * 4 + oct;
    const int fragaddr = (((jj >> 5) * 64 + ((jj >> 3) & 3) * 16 + m) << 3) + (jj & 7);
    unsigned short* houtp = h1rm + ((size_t)(g * 16 + m) * T_) * HP_ + jj;
    const float* xrow = x + ((size_t)(g * 16 + m) * T_) * IN_ + (oct & 1) * 8;
    const short8* xq = wg1 + (size_t)wtile * (KSR_ * 64) + lane;
    const short8* wl = &wlds[wave * (KSR_ * 64) + lane];
    const short8* al = &alds[lane];
    const short8* a0l = &a0lds[lane];
    const short8 z8 = {0, 0, 0, 0, 0, 0, 0, 0};

    __syncthreads();   // wlds/alds/gate ready

    float c = 0.f;

    #pragma unroll 1
    for (int t = 0; t < T_; ++t) {
        f32x4 accC = {0.f, 0.f, 0.f, 0.f}, accD = {0.f, 0.f, 0.f, 0.f};
        short8 xw[KSR_];   // L1: Wih1 prefetch (fully unrolled -> registers)

        if (layer == 0) {
            // x contribution (independent of recurrence, pre-poll)
            const float* xr = xrow + (size_t)t * IN_;
            f32x4 xf0 = *(const f32x4*)xr;
            f32x4 xf1 = *(const f32x4*)(xr + 4);
            S8U xu;
            xu.u[0] = (uint32)f2bf(xf0[0]) | ((uint32)f2bf(xf0[1]) << 16);
            xu.u[1] = (uint32)f2bf(xf0[2]) | ((uint32)f2bf(xf0[3]) << 16);
            xu.u[2] = (uint32)f2bf(xf1[0]) | ((uint32)f2bf(xf1[1]) << 16);
            xu.u[3] = (uint32)f2bf(xf1[2]) | ((uint32)f2bf(xf1[3]) << 16);
            short8 xa = (oct < 2) ? xu.s : z8;
            MF(wxv, xa, accC);

            if (t > 0) {
                // release: own flags >= t (h0[t-1] ready); L1 >= t-7 (slot free)
                if (wave == 0) {
                    poll75x2(f0, f1, t, t - 7, lane);
                    if (lane == 0) *(volatile int*)&gate = t;
                } else {
                    int it = 0;
                    while (*(volatile int*)&gate < t) {
                        __builtin_amdgcn_s_sleep(1);
                        if (++it > (1 << 24)) break;
                    }
                }
                const unsigned short* sp = r0g + (size_t)((t - 1) & (RS0_ - 1)) * 5120
                                         + wave * 512 + lane * 8;
                short8 v = ld16c(sp);
                vm0();
                alds[wave * 64 + lane] = v;
                __syncthreads();
            }
        } else {
            // prefetch Wih1 fragments (same addresses every step -> L1/L2-hot)
            #pragma unroll
            for (int s = 0; s < KSR_; ++s) xw[s] = xq[s * 64];

            // release: L0 flags >= t+1 (h0[t] ready); own >= t (h1[t-1] ready)
            if (wave == 0) {
                poll75x2(f0, f1, t + 1, t, lane);
                if (lane == 0) *(volatile int*)&gate = t;
            } else {
                int it = 0;
                while (*(volatile int*)&gate < t) {
                    __builtin_amdgcn_s_sleep(1);
                    if (++it > (1 << 24)) break;
                }
            }
            {
                const unsigned short* sp0 = r0g + (size_t)(t & (RS0_ - 1)) * 5120
                                          + wave * 512 + lane * 8;
                short8 v0 = ld16c(sp0);
                if (t > 0) {
                    const unsigned short* sp1 = r1g + (size_t)((t - 1) & 1) * 5120
                                              + wave * 512 + lane * 8;
                    short8 v1 = ld16c(sp1);
                    vm0();
                    a0lds[wave * 64 + lane] = v0;
                    alds[wave * 64 + lane] = v1;
                } else {
                    vm0();
                    a0lds[wave * 64 + lane] = v0;
                }
            }
            __syncthreads();
            // Wih1 @ h0[t] from prefetched regs + staged LDS
            #pragma unroll
            for (int s = 0; s < KSR_; s += 2) {
                MF(xw[s],     a0l[s * 64],       accC);
                MF(xw[s + 1], a0l[(s + 1) * 64], accD);
            }
        }

        // recurrent part: Whh @ h[t-1] from LDS
        f32x4 accA = {0.f, 0.f, 0.f, 0.f}, accB = {0.f, 0.f, 0.f, 0.f};
        #pragma unroll
        for (int s = 0; s < KSR_; s += 2) {
            MF(wl[s * 64],       al[s * 64],       accA);
            MF(wl[(s + 1) * 64], al[(s + 1) * 64], accB);
        }

        float gi = sigm(accA[0] + accB[0] + accC[0] + accD[0] + b4[0]);
        float gf = sigm(accA[1] + accB[1] + accC[1] + accD[1] + b4[1]);
        float gg = tanh_f(accA[2] + accB[2] + accC[2] + accD[2] + b4[2]);
        float go = sigm(accA[3] + accB[3] + accC[3] + accD[3] + b4[3]);
        float cn = gf * c + gi * gg;
        c = cn;
        unsigned short hb = f2bf(go * tanh_f(cn));
        if (act) {
            if (layer == 0) {
                st2c(r0g + (size_t)(t & (RS0_ - 1)) * 5120 + fragaddr, hb);
            } else {
                st2c(r1g + (size_t)(t & 1) * 5120 + fragaddr, hb);
                houtp[(size_t)t * HP_] = hb;       // row-major for head
            }
            vm0();                                 // data at IF$ before flag
            if (lane == 0) st4c(fown, t + 1);      // publish epoch (per wave)
        }
    }
}

// ---------------------------------------------------------------------------
// MLP head: W1/W2/W3 staged in LDS (broadcast reads), one thread per position.
// ---------------------------------------------------------------------------
__global__ __launch_bounds__(256) void head_kernel(
    const unsigned short* __restrict__ h1,
    const float* __restrict__ W1, const float* __restrict__ b1,
    const float* __restrict__ W2, const float* __restrict__ b2,
    const float* __restrict__ W3, const float* __restrict__ b3,
    float* __restrict__ out)
{
    __shared__ float w1s[9000];     // 30x300
    __shared__ float w2s[3200];     // 100x32 (padded)
    __shared__ float w3s[100];
    __shared__ float b1s[30];
    __shared__ float b2s[100];
    const int tid = threadIdx.x;
    for (int i = tid; i < 9000; i += 256) w1s[i] = W1[i];
    for (int i = tid; i < 3000; i += 256) w2s[(i / 30) * 32 + (i % 30)] = W2[i];
    if (tid < 100) { w3s[tid] = W3[tid]; b2s[tid] = b2[tid]; }
    if (tid < 30)  b1s[tid] = b1[tid];
    __syncthreads();

    const int pos = blockIdx.x * 256 + tid;
    const unsigned short* hr = h1 + (size_t)pos * HP_;
    float t1[30];
    #pragma unroll
    for (int j = 0; j < 30; ++j) t1[j] = b1s[j];
    for (int kc = 0; kc < H_; kc += 4) {
        uint32 u0 = *(const uint32*)(hr + kc);
        uint32 u1 = *(const uint32*)(hr + kc + 2);
        float h0v = bf2f((unsigned short)(u0 & 0xffffu));
        float h1v = bf2f((unsigned short)(u0 >> 16));
        float h2v = bf2f((unsigned short)(u1 & 0xffffu));
        float h3v = bf2f((unsigned short)(u1 >> 16));
        #pragma unroll
        for (int j = 0; j < 30; ++j) {
            const f32x4 wv = *(const f32x4*)&w1s[j * H_ + kc];
            t1[j] += h0v * wv[0] + h1v * wv[1] + h2v * wv[2] + h3v * wv[3];
        }
    }
    #pragma unroll
    for (int j = 0; j < 30; ++j) t1[j] = tanh_f(t1[j]);
    float oacc = b3[0];
    for (int j2 = 0; j2 < 100; ++j2) {
        float a2 = b2s[j2];
        #pragma unroll
        for (int k = 0; k < 30; ++k) a2 += t1[k] * w2s[j2 * 32 + k];
        oacc += tanh_f(a2) * w3s[j2];
    }
    out[pos] = sigm(oacc);
}

// ---------------------------------------------------------------------------
extern "C" void kernel_launch(void* const* d_in, const int* in_sizes, int n_in,
                              void* d_out, int out_size, void* d_ws, size_t ws_size,
                              hipStream_t stream)
{
    const float* x    = (const float*)d_in[0];
    const float* Wih0 = (const float*)d_in[1];
    const float* Whh0 = (const float*)d_in[2];
    const float* bih0 = (const float*)d_in[3];
    const float* bhh0 = (const float*)d_in[4];
    const float* Wih1 = (const float*)d_in[5];
    const float* Whh1 = (const float*)d_in[6];
    const float* bih1 = (const float*)d_in[7];
    const float* bhh1 = (const float*)d_in[8];
    const float* W1   = (const float*)d_in[9];
    const float* b1   = (const float*)d_in[10];
    const float* W2   = (const float*)d_in[11];
    const float* b2   = (const float*)d_in[12];
    const float* W3   = (const float*)d_in[13];
    const float* b3   = (const float*)d_in[14];

    // buffers sized for 80 tiles so member-7 blocks can bulk-copy safely
    char* ws = (char*)d_ws;
    const size_t OFF_WR0 = 0x000000;   // 819200 B
    const size_t OFF_WG0 = 0x0D0000;   // 81920 B
    const size_t OFF_WR1 = 0x0E8000;   // 819200 B
    const size_t OFF_WG1 = 0x1B0000;   // 819200 B
    const size_t OFF_B0  = 0x280000;   // 4800 B
    const size_t OFF_B1  = 0x282000;   // 4800 B
    const size_t OFF_FLG = 0x284000;   // 2 x 16 x 128 x 4 = 16384 B
    const size_t OFF_RG0 = 0x290000;   // 16 x 8 x 10240 B = 1310720
    const size_t OFF_RG1 = 0x3D0000;   // 16 x 2 x 10240 B = 327680
    const size_t OFF_H1  = 0x420000;   // 41,943,040 B
    const size_t HB      = (size_t)B_ * T_ * HP_ * 2;
    const size_t NEED    = OFF_H1 + HB;          // ~46 MB
    if (ws_size < NEED) return;

    uint32* wr0 = (uint32*)(ws + OFF_WR0);
    uint32* wg0 = (uint32*)(ws + OFF_WG0);
    uint32* wr1 = (uint32*)(ws + OFF_WR1);
    uint32* wg1 = (uint32*)(ws + OFF_WG1);
    float*  b0p = (float*)(ws + OFF_B0);
    float*  b1p = (float*)(ws + OFF_B1);
    int*    flg = (int*)(ws + OFF_FLG);
    unsigned short* rg0 = (unsigned short*)(ws + OFF_RG0);
    unsigned short* rg1 = (unsigned short*)(ws + OFF_RG1);
    unsigned short* h1b = (unsigned short*)(ws + OFF_H1);

    hipMemsetAsync(ws + OFF_FLG, 0, 16384, stream);   // flags -> epoch 0

    hipLaunchKernelGGL(pack_kernel, dim3(591), dim3(256), 0, stream,
                       Wih0, Whh0, bih0, bhh0, Wih1, Whh1, bih1, bhh1,
                       wr0, wg0, wr1, wg1, b0p, b1p);
    hipLaunchKernelGGL(lstm_dual, dim3(256), dim3(640), 0, stream,
                       x, (const short8*)wr0, (const short8*)wg0,
                       (const short8*)wr1, (const short8*)wg1,
                       b0p, b1p, h1b, rg0, rg1, flg);
    hipLaunchKernelGGL(head_kernel, dim3(256), dim3(256), 0, stream,
                       h1b, W1, b1, W2, b2, W3, b3, (float*)d_out);
}

// Round 13
// 983.680 us; speedup vs baseline: 2.1712x; 2.1712x over previous
//
#include <hip/hip_runtime.h>

#define B_ 256
#define T_ 256
#define H_ 300
#define IN_ 16
#define NT_ 75          // gate tiles (1200/16)
#define KSR_ 10         // recurrent K slabs (300 -> 320)
#define HP_ 320         // padded h row stride (elements)
#define MEMB_ 8         // member blocks per group per layer
#define WPB_ 10         // waves per block (640 threads)
#define RS0_ 8          // ring-0 slots (h0), power of 2

typedef __attribute__((ext_vector_type(8))) short short8;
typedef __attribute__((ext_vector_type(4))) float f32x4;
typedef unsigned int uint32;

union S8U { short8 s; uint32 u[4]; };

__device__ __forceinline__ unsigned short f2bf(float f) {
    uint32 u = __float_as_uint(f);
    u = u + 0x7fffu + ((u >> 16) & 1u);   // RNE
    return (unsigned short)(u >> 16);
}
__device__ __forceinline__ float bf2f(unsigned short h) {
    return __uint_as_float(((uint32)h) << 16);
}
__device__ __forceinline__ float sigm(float x) {
    float e = __expf(-x);
    return __builtin_amdgcn_rcpf(1.f + e);
}
__device__ __forceinline__ float tanh_f(float x) {
    float xc = fminf(fmaxf(x, -15.f), 15.f);
    float e = __expf(2.f * xc);
    return (e - 1.f) * __builtin_amdgcn_rcpf(e + 1.f);
}

// IF$ (coherence-point) ops: sc0 sc1 bypass L1/L2 -> coherent across XCDs,
// zero cache-maintenance. Used ONLY for the per-step exchange.
__device__ __forceinline__ short8 ld16c(const void* p) {
    short8 r;
    asm volatile("global_load_dwordx4 %0, %1, off sc0 sc1"
                 : "=v"(r) : "v"(p));
    return r;
}
__device__ __forceinline__ void st2c(unsigned short* p, unsigned short v) {
    uint32 vv = v;
    asm volatile("global_store_short %0, %1, off sc0 sc1" :: "v"(p), "v"(vv) : "memory");
}
__device__ __forceinline__ void atomic_inc_cg(int* p) {
    int one = 1;
    asm volatile("global_atomic_add %0, %1, off sc1" :: "v"(p), "v"(one) : "memory");
}
__device__ __forceinline__ void vm0() {
    asm volatile("s_waitcnt vmcnt(0)" ::: "memory");
}
// dual-counter poll (one IF$ round trip per iteration)
__device__ __forceinline__ void poll2(const int* p0, const int* p1, int ta, int tb) {
    int it = 0;
    for (;;) {
        int c0, c1;
        asm volatile("global_load_dword %0, %2, off sc0 sc1\n\t"
                     "global_load_dword %1, %3, off sc0 sc1\n\t"
                     "s_waitcnt vmcnt(0)"
                     : "=&v"(c0), "=&v"(c1) : "v"(p0), "v"(p1) : "memory");
        if (c0 >= ta && c1 >= tb) break;
        __builtin_amdgcn_s_sleep(1);
        if (++it > (1 << 22)) break;   // bailout: wrong > hung
    }
}

#define MF(w_, a_, acc_) acc_ = __builtin_amdgcn_mfma_f32_16x16x32_bf16(w_, a_, acc_, 0, 0, 0)

// ---------------------------------------------------------------------------
// Weight packing into bf16 MFMA A-fragments, gate rows permuted unit-major.
// ---------------------------------------------------------------------------
__device__ __forceinline__ void pack_one(int idx, const float* __restrict__ W,
                                         int K, int KS, uint32* __restrict__ dst)
{
    int lane = idx & 63, ts = idx >> 6;
    int slab = ts % KS, tile = ts / KS;
    int rp = tile * 16 + (lane & 15);
    int jj = rp >> 2, g = rp & 3;
    int r = g * H_ + jj;
    int kb = slab * 32 + (lane >> 4) * 8;
    #pragma unroll
    for (int p = 0; p < 4; ++p) {
        int k0 = kb + 2 * p, k1 = k0 + 1;
        float v0 = (k0 < K) ? W[(size_t)r * K + k0] : 0.f;
        float v1 = (k1 < K) ? W[(size_t)r * K + k1] : 0.f;
        dst[(size_t)idx * 4 + p] = (uint32)f2bf(v0) | ((uint32)f2bf(v1) << 16);
    }
}

__global__ void pack_kernel(const float* __restrict__ Wih0, const float* __restrict__ Whh0,
                            const float* __restrict__ bih0, const float* __restrict__ bhh0,
                            const float* __restrict__ Wih1, const float* __restrict__ Whh1,
                            const float* __restrict__ bih1, const float* __restrict__ bhh1,
                            uint32* __restrict__ wr0, uint32* __restrict__ wg0,
                            uint32* __restrict__ wr1, uint32* __restrict__ wg1,
                            float* __restrict__ b0p, float* __restrict__ b1p)
{
    const int C0 = NT_ * KSR_ * 64;   // 48000
    const int C1 = NT_ * 64;          // 4800
    int id = blockIdx.x * 256 + threadIdx.x;
    if (id < C0) pack_one(id, Whh0, H_, KSR_, wr0);
    else if (id < C0 + C1) pack_one(id - C0, Wih0, IN_, 1, wg0);
    else if (id < 2 * C0 + C1) pack_one(id - C0 - C1, Whh1, H_, KSR_, wr1);
    else if (id < 3 * C0 + C1) pack_one(id - 2 * C0 - C1, Wih1, H_, KSR_, wg1);
    else if (id < 3 * C0 + C1 + 1200) {
        int p = id - 3 * C0 - C1;
        int jj = p >> 2, g = p & 3, r = g * H_ + jj;
        b0p[p] = bih0[r] + bhh0[r];
    } else if (id < 3 * C0 + C1 + 2400) {
        int p = id - 3 * C0 - C1 - 1200;
        int jj = p >> 2, g = p & 3, r = g * H_ + jj;
        b1p[p] = bih1[r] + bhh1[r];
    }
}

// ---------------------------------------------------------------------------
// BOTH LSTM layers in one dispatch, software-pipelined: 256 blocks x 640.
// blocks 0..127: layer 0; 128..255: layer 1 (lagging 1 step).
// r11 protocol (block counters, tid0 poll2, stage->barrier) with two fixes:
//  - ring0 8-deep: L0 back-pressure >= t-7, decoupled from L1 notice jitter
//  - publish via LDS monotonic counter: wave stores h -> vmcnt0 -> lane0
//    ds_atomic_add; the 10th wave fires the group-counter inc. No trailing
//    barrier; counter fires the moment the last wave's data is at IF$.
// ---------------------------------------------------------------------------
__global__ __launch_bounds__(640) void lstm_dual(
    const float* __restrict__ x,
    const short8* __restrict__ wr0, const short8* __restrict__ wg0,
    const short8* __restrict__ wr1, const short8* __restrict__ wg1,
    const float* __restrict__ b0p, const float* __restrict__ b1p,
    unsigned short* __restrict__ h1rm,
    unsigned short* __restrict__ ring0, unsigned short* __restrict__ ring1,
    int* __restrict__ cnt)
{
    __shared__ short8 wlds[WPB_ * KSR_ * 64];   // 100 KB: Whh tiles
    __shared__ short8 alds[KSR_ * 64];          // 10 KB: own-layer h state
    __shared__ short8 a0lds[KSR_ * 64];         // 10 KB: h0[t] (layer 1 only)
    __shared__ int lcnt;                        // monotonic publish counter

    const int tid = threadIdx.x;
    const int wave = tid >> 6, lane = tid & 63;
    const int layer = (int)(blockIdx.x >> 7);
    const int lb = blockIdx.x & 127;
    const int g = lb & 15, member = lb >> 4;
    const int rawwt = member * WPB_ + wave;      // 0..79
    const bool act = rawwt < NT_;
    const int wtile = act ? rawwt : NT_ - 1;
    const int m = lane & 15, oct = lane >> 4;

    {   // one-time: weights -> LDS; zero own-state buffer (h[-1] = 0); lcnt=0
        const short8* wsrc = (layer ? wr1 : wr0) + (size_t)member * (WPB_ * KSR_ * 64);
        for (int i = tid; i < WPB_ * KSR_ * 64; i += 640) wlds[i] = wsrc[i];
        short8 z = {0, 0, 0, 0, 0, 0, 0, 0};
        if (tid < KSR_ * 64) alds[tid] = z;
        if (tid == 0) lcnt = 0;
    }
    short8 wxv;
    if (layer == 0) wxv = wg0[(size_t)wtile * 64 + lane];
    const float* bp = layer ? b1p : b0p;
    const f32x4 b4 = *(const f32x4*)&bp[wtile * 16 + oct * 4];

    unsigned short* r0g = ring0 + (size_t)g * (RS0_ * 5120);
    unsigned short* r1g = ring1 + (size_t)g * (2 * 5120);
    int* c0 = cnt + g * 16;
    int* c1 = cnt + 1024 + g * 16;
    int* cown = layer ? c1 : c0;

    const int jj = wtile * 4 + oct;
    const int fragaddr = (((jj >> 5) * 64 + ((jj >> 3) & 3) * 16 + m) << 3) + (jj & 7);
    unsigned short* houtp = h1rm + ((size_t)(g * 16 + m) * T_) * HP_ + jj;
    const float* xrow = x + ((size_t)(g * 16 + m) * T_) * IN_ + (oct & 1) * 8;
    const short8* xq = wg1 + (size_t)wtile * (KSR_ * 64) + lane;
    const short8* wl = &wlds[wave * (KSR_ * 64) + lane];
    const short8* al = &alds[lane];
    const short8* a0l = &a0lds[lane];
    const short8 z8 = {0, 0, 0, 0, 0, 0, 0, 0};

    __syncthreads();   // wlds/alds/lcnt ready

    float c = 0.f;

    #pragma unroll 1
    for (int t = 0; t < T_; ++t) {
        f32x4 accC = {0.f, 0.f, 0.f, 0.f}, accD = {0.f, 0.f, 0.f, 0.f};

        if (layer == 0) {
            // x contribution (independent of recurrence, pre-poll)
            const float* xr = xrow + (size_t)t * IN_;
            f32x4 xf0 = *(const f32x4*)xr;
            f32x4 xf1 = *(const f32x4*)(xr + 4);
            S8U xu;
            xu.u[0] = (uint32)f2bf(xf0[0]) | ((uint32)f2bf(xf0[1]) << 16);
            xu.u[1] = (uint32)f2bf(xf0[2]) | ((uint32)f2bf(xf0[3]) << 16);
            xu.u[2] = (uint32)f2bf(xf1[0]) | ((uint32)f2bf(xf1[1]) << 16);
            xu.u[3] = (uint32)f2bf(xf1[2]) | ((uint32)f2bf(xf1[3]) << 16);
            short8 xa = (oct < 2) ? xu.s : z8;
            MF(wxv, xa, accC);

            if (t > 0) {
                // need: all members published h0[t-1]; L1 consumed h0[t-8]
                if (tid == 0) poll2(c0, c1, MEMB_ * t, MEMB_ * (t - 7));
                __syncthreads();
                const unsigned short* sp = r0g + (size_t)((t - 1) & (RS0_ - 1)) * 5120
                                         + wave * 512 + lane * 8;
                short8 v = ld16c(sp);
                vm0();
                alds[wave * 64 + lane] = v;
                __syncthreads();
            }
        } else {
            // need: h0[t] published; own members published h1[t-1]
            if (tid == 0) poll2(c0, c1, MEMB_ * (t + 1), MEMB_ * t);
            __syncthreads();
            {
                const unsigned short* sp0 = r0g + (size_t)(t & (RS0_ - 1)) * 5120
                                          + wave * 512 + lane * 8;
                short8 v0 = ld16c(sp0);
                if (t > 0) {
                    const unsigned short* sp1 = r1g + (size_t)((t - 1) & 1) * 5120
                                              + wave * 512 + lane * 8;
                    short8 v1 = ld16c(sp1);
                    vm0();
                    a0lds[wave * 64 + lane] = v0;
                    alds[wave * 64 + lane] = v1;
                } else {
                    vm0();
                    a0lds[wave * 64 + lane] = v0;
                }
            }
            __syncthreads();
            // Wih1 @ h0[t] (weights stream from L1/L2, constant addresses)
            #pragma unroll
            for (int s = 0; s < KSR_; s += 2) {
                MF(xq[s * 64],       a0l[s * 64],       accC);
                MF(xq[(s + 1) * 64], a0l[(s + 1) * 64], accD);
            }
        }

        // recurrent part: Whh @ h[t-1] from LDS
        f32x4 accA = {0.f, 0.f, 0.f, 0.f}, accB = {0.f, 0.f, 0.f, 0.f};
        #pragma unroll
        for (int s = 0; s < KSR_; s += 2) {
            MF(wl[s * 64],       al[s * 64],       accA);
            MF(wl[(s + 1) * 64], al[(s + 1) * 64], accB);
        }

        float gi = sigm(accA[0] + accB[0] + accC[0] + accD[0] + b4[0]);
        float gf = sigm(accA[1] + accB[1] + accC[1] + accD[1] + b4[1]);
        float gg = tanh_f(accA[2] + accB[2] + accC[2] + accD[2] + b4[2]);
        float go = sigm(accA[3] + accB[3] + accC[3] + accD[3] + b4[3]);
        float cn = gf * c + gi * gg;
        c = cn;
        unsigned short hb = f2bf(go * tanh_f(cn));
        if (act) {
            if (layer == 0) {
                st2c(r0g + (size_t)(t & (RS0_ - 1)) * 5120 + fragaddr, hb);
            } else {
                st2c(r1g + (size_t)(t & 1) * 5120 + fragaddr, hb);
                houtp[(size_t)t * HP_] = hb;       // row-major for head
            }
        }
        vm0();   // own h stores at IF$ before counting this wave as done
        if (lane == 0) {
            int old = atomicAdd(&lcnt, 1);         // LDS, monotonic
            if (old == WPB_ * (t + 1) - 1)         // last wave of this step
                atomic_inc_cg(cown);
        }
    }
}

// ---------------------------------------------------------------------------
// MLP head: W1/W2/W3 staged in LDS (broadcast reads), one thread per position.
// ---------------------------------------------------------------------------
__global__ __launch_bounds__(256) void head_kernel(
    const unsigned short* __restrict__ h1,
    const float* __restrict__ W1, const float* __restrict__ b1,
    const float* __restrict__ W2, const float* __restrict__ b2,
    const float* __restrict__ W3, const float* __restrict__ b3,
    float* __restrict__ out)
{
    __shared__ float w1s[9000];     // 30x300
    __shared__ float w2s[3200];     // 100x32 (padded)
    __shared__ float w3s[100];
    __shared__ float b1s[30];
    __shared__ float b2s[100];
    const int tid = threadIdx.x;
    for (int i = tid; i < 9000; i += 256) w1s[i] = W1[i];
    for (int i = tid; i < 3000; i += 256) w2s[(i / 30) * 32 + (i % 30)] = W2[i];
    if (tid < 100) { w3s[tid] = W3[tid]; b2s[tid] = b2[tid]; }
    if (tid < 30)  b1s[tid] = b1[tid];
    __syncthreads();

    const int pos = blockIdx.x * 256 + tid;
    const unsigned short* hr = h1 + (size_t)pos * HP_;
    float t1[30];
    #pragma unroll
    for (int j = 0; j < 30; ++j) t1[j] = b1s[j];
    for (int kc = 0; kc < H_; kc += 4) {
        uint32 u0 = *(const uint32*)(hr + kc);
        uint32 u1 = *(const uint32*)(hr + kc + 2);
        float h0v = bf2f((unsigned short)(u0 & 0xffffu));
        float h1v = bf2f((unsigned short)(u0 >> 16));
        float h2v = bf2f((unsigned short)(u1 & 0xffffu));
        float h3v = bf2f((unsigned short)(u1 >> 16));
        #pragma unroll
        for (int j = 0; j < 30; ++j) {
            const f32x4 wv = *(const f32x4*)&w1s[j * H_ + kc];
            t1[j] += h0v * wv[0] + h1v * wv[1] + h2v * wv[2] + h3v * wv[3];
        }
    }
    #pragma unroll
    for (int j = 0; j < 30; ++j) t1[j] = tanh_f(t1[j]);
    float oacc = b3[0];
    for (int j2 = 0; j2 < 100; ++j2) {
        float a2 = b2s[j2];
        #pragma unroll
        for (int k = 0; k < 30; ++k) a2 += t1[k] * w2s[j2 * 32 + k];
        oacc += tanh_f(a2) * w3s[j2];
    }
    out[pos] = sigm(oacc);
}

// ---------------------------------------------------------------------------
extern "C" void kernel_launch(void* const* d_in, const int* in_sizes, int n_in,
                              void* d_out, int out_size, void* d_ws, size_t ws_size,
                              hipStream_t stream)
{
    const float* x    = (const float*)d_in[0];
    const float* Wih0 = (const float*)d_in[1];
    const float* Whh0 = (const float*)d_in[2];
    const float* bih0 = (const float*)d_in[3];
    const float* bhh0 = (const float*)d_in[4];
    const float* Wih1 = (const float*)d_in[5];
    const float* Whh1 = (const float*)d_in[6];
    const float* bih1 = (const float*)d_in[7];
    const float* bhh1 = (const float*)d_in[8];
    const float* W1   = (const float*)d_in[9];
    const float* b1   = (const float*)d_in[10];
    const float* W2   = (const float*)d_in[11];
    const float* b2   = (const float*)d_in[12];
    const float* W3   = (const float*)d_in[13];
    const float* b3   = (const float*)d_in[14];

    // buffers sized for 80 tiles so member-7 blocks can bulk-copy safely
    char* ws = (char*)d_ws;
    const size_t OFF_WR0 = 0x000000;   // 819200 B
    const size_t OFF_WG0 = 0x0D0000;   // 81920 B
    const size_t OFF_WR1 = 0x0E8000;   // 819200 B
    const size_t OFF_WG1 = 0x1B0000;   // 819200 B
    const size_t OFF_B0  = 0x280000;   // 4800 B
    const size_t OFF_B1  = 0x282000;   // 4800 B
    const size_t OFF_CNT = 0x284000;   // c0 @ +0 (1KB), c1 @ +4KB (1KB)
    const size_t OFF_RG0 = 0x290000;   // 16 x 8 x 10240 B = 1310720
    const size_t OFF_RG1 = 0x3D0000;   // 16 x 2 x 10240 B = 327680
    const size_t OFF_H1  = 0x420000;   // 41,943,040 B
    const size_t HB      = (size_t)B_ * T_ * HP_ * 2;
    const size_t NEED    = OFF_H1 + HB;          // ~46 MB
    if (ws_size < NEED) return;

    uint32* wr0 = (uint32*)(ws + OFF_WR0);
    uint32* wg0 = (uint32*)(ws + OFF_WG0);
    uint32* wr1 = (uint32*)(ws + OFF_WR1);
    uint32* wg1 = (uint32*)(ws + OFF_WG1);
    float*  b0p = (float*)(ws + OFF_B0);
    float*  b1p = (float*)(ws + OFF_B1);
    int*    cnt = (int*)(ws + OFF_CNT);
    unsigned short* rg0 = (unsigned short*)(ws + OFF_RG0);
    unsigned short* rg1 = (unsigned short*)(ws + OFF_RG1);
    unsigned short* h1b = (unsigned short*)(ws + OFF_H1);

    hipMemsetAsync(ws + OFF_CNT, 0, 8192, stream);   // counters -> epoch 0

    hipLaunchKernelGGL(pack_kernel, dim3(591), dim3(256), 0, stream,
                       Wih0, Whh0, bih0, bhh0, Wih1, Whh1, bih1, bhh1,
                       wr0, wg0, wr1, wg1, b0p, b1p);
    hipLaunchKernelGGL(lstm_dual, dim3(256), dim3(640), 0, stream,
                       x, (const short8*)wr0, (const short8*)wg0,
                       (const short8*)wr1, (const short8*)wg1,
                       b0p, b1p, h1b, rg0, rg1, cnt);
    hipLaunchKernelGGL(head_kernel, dim3(256), dim3(256), 0, stream,
                       h1b, W1, b1, W2, b2, W3, b3, (float*)d_out);
}

// Round 15
// 961.864 us; speedup vs baseline: 2.2204x; 1.0227x over previous
//
#include <hip/hip_runtime.h>

#define B_ 256
#define T_ 256
#define H_ 300
#define IN_ 16
#define NT_ 75          // gate tiles (1200/16)
#define KSR_ 10         // recurrent K slabs (300 -> 320)
#define HP_ 320         // padded h row stride (elements)
#define MEMB_ 8         // member blocks per group per layer
#define WPB_ 10         // waves per block (640 threads)
#define RS0_ 8          // ring-0 slots (h0), power of 2

typedef __attribute__((ext_vector_type(8))) short short8;
typedef __attribute__((ext_vector_type(4))) float f32x4;
typedef unsigned int uint32;

union S8U { short8 s; uint32 u[4]; };

__device__ __forceinline__ unsigned short f2bf(float f) {
    uint32 u = __float_as_uint(f);
    u = u + 0x7fffu + ((u >> 16) & 1u);   // RNE
    return (unsigned short)(u >> 16);
}
__device__ __forceinline__ float bf2f(unsigned short h) {
    return __uint_as_float(((uint32)h) << 16);
}
__device__ __forceinline__ float sigm(float x) {
    float e = __expf(-x);
    return __builtin_amdgcn_rcpf(1.f + e);
}
__device__ __forceinline__ float tanh_f(float x) {
    float xc = fminf(fmaxf(x, -15.f), 15.f);
    float e = __expf(2.f * xc);
    return (e - 1.f) * __builtin_amdgcn_rcpf(e + 1.f);
}

// IF$ (coherence-point) ops: sc0 sc1 bypass L1/L2 -> coherent across XCDs,
// zero cache-maintenance. Used ONLY for the per-step exchange.
__device__ __forceinline__ short8 ld16c(const void* p) {
    short8 r;
    asm volatile("global_load_dwordx4 %0, %1, off sc0 sc1"
                 : "=v"(r) : "v"(p));
    return r;
}
__device__ __forceinline__ void st2c(unsigned short* p, unsigned short v) {
    uint32 vv = v;
    asm volatile("global_store_short %0, %1, off sc0 sc1" :: "v"(p), "v"(vv) : "memory");
}
__device__ __forceinline__ void atomic_inc_cg(int* p) {
    int one = 1;
    asm volatile("global_atomic_add %0, %1, off sc1" :: "v"(p), "v"(one) : "memory");
}
__device__ __forceinline__ void vm0() {
    asm volatile("s_waitcnt vmcnt(0)" ::: "memory");
}
// single-counter poll (one IF$ round trip per iteration)
__device__ __forceinline__ void poll1(const int* p0, int ta) {
    int it = 0;
    for (;;) {
        int c0;
        asm volatile("global_load_dword %0, %1, off sc0 sc1\n\ts_waitcnt vmcnt(0)"
                     : "=&v"(c0) : "v"(p0) : "memory");
        if (c0 >= ta) break;
        __builtin_amdgcn_s_sleep(1);
        if (++it > (1 << 22)) break;   // bailout: wrong > hung
    }
}
// dual-counter poll (one IF$ round trip per iteration)
__device__ __forceinline__ void poll2(const int* p0, const int* p1, int ta, int tb) {
    int it = 0;
    for (;;) {
        int c0, c1;
        asm volatile("global_load_dword %0, %2, off sc0 sc1\n\t"
                     "global_load_dword %1, %3, off sc0 sc1\n\t"
                     "s_waitcnt vmcnt(0)"
                     : "=&v"(c0), "=&v"(c1) : "v"(p0), "v"(p1) : "memory");
        if (c0 >= ta && c1 >= tb) break;
        __builtin_amdgcn_s_sleep(1);
        if (++it > (1 << 22)) break;   // bailout: wrong > hung
    }
}

#define MF(w_, a_, acc_) acc_ = __builtin_amdgcn_mfma_f32_16x16x32_bf16(w_, a_, acc_, 0, 0, 0)

// ---------------------------------------------------------------------------
// Weight packing into bf16 MFMA A-fragments, gate rows permuted unit-major.
// ---------------------------------------------------------------------------
__device__ __forceinline__ void pack_one(int idx, const float* __restrict__ W,
                                         int K, int KS, uint32* __restrict__ dst)
{
    int lane = idx & 63, ts = idx >> 6;
    int slab = ts % KS, tile = ts / KS;
    int rp = tile * 16 + (lane & 15);
    int jj = rp >> 2, g = rp & 3;
    int r = g * H_ + jj;
    int kb = slab * 32 + (lane >> 4) * 8;
    #pragma unroll
    for (int p = 0; p < 4; ++p) {
        int k0 = kb + 2 * p, k1 = k0 + 1;
        float v0 = (k0 < K) ? W[(size_t)r * K + k0] : 0.f;
        float v1 = (k1 < K) ? W[(size_t)r * K + k1] : 0.f;
        dst[(size_t)idx * 4 + p] = (uint32)f2bf(v0) | ((uint32)f2bf(v1) << 16);
    }
}

__global__ void pack_kernel(const float* __restrict__ Wih0, const float* __restrict__ Whh0,
                            const float* __restrict__ bih0, const float* __restrict__ bhh0,
                            const float* __restrict__ Wih1, const float* __restrict__ Whh1,
                            const float* __restrict__ bih1, const float* __restrict__ bhh1,
                            uint32* __restrict__ wr0, uint32* __restrict__ wg0,
                            uint32* __restrict__ wr1, uint32* __restrict__ wg1,
                            float* __restrict__ b0p, float* __restrict__ b1p)
{
    const int C0 = NT_ * KSR_ * 64;   // 48000
    const int C1 = NT_ * 64;          // 4800
    int id = blockIdx.x * 256 + threadIdx.x;
    if (id < C0) pack_one(id, Whh0, H_, KSR_, wr0);
    else if (id < C0 + C1) pack_one(id - C0, Wih0, IN_, 1, wg0);
    else if (id < 2 * C0 + C1) pack_one(id - C0 - C1, Whh1, H_, KSR_, wr1);
    else if (id < 3 * C0 + C1) pack_one(id - 2 * C0 - C1, Wih1, H_, KSR_, wg1);
    else if (id < 3 * C0 + C1 + 1200) {
        int p = id - 3 * C0 - C1;
        int jj = p >> 2, g = p & 3, r = g * H_ + jj;
        b0p[p] = bih0[r] + bhh0[r];
    } else if (id < 3 * C0 + C1 + 2400) {
        int p = id - 3 * C0 - C1 - 1200;
        int jj = p >> 2, g = p & 3, r = g * H_ + jj;
        b1p[p] = bih1[r] + bhh1[r];
    }
}

// ---------------------------------------------------------------------------
// BOTH LSTM layers in one dispatch, software-pipelined: 256 blocks x 640.
// blocks 0..127: layer 0; 128..255: layer 1 (lagging 1 step).
// r13 protocol (IF$ sc0sc1 exchange, block counters, LDS publish counter,
// ring0 8-deep) with L1 SPLIT-POLL: the h0[t] stage + Wih1 chain run under
// the (almost always open) c0 gate BEFORE the binding c1 poll, so the
// publish->visible fabric latency overlaps useful work.
// ---------------------------------------------------------------------------
__global__ __launch_bounds__(640) void lstm_dual(
    const float* __restrict__ x,
    const short8* __restrict__ wr0, const short8* __restrict__ wg0,
    const short8* __restrict__ wr1, const short8* __restrict__ wg1,
    const float* __restrict__ b0p, const float* __restrict__ b1p,
    unsigned short* __restrict__ h1rm,
    unsigned short* __restrict__ ring0, unsigned short* __restrict__ ring1,
    int* __restrict__ cnt)
{
    __shared__ short8 wlds[WPB_ * KSR_ * 64];   // 100 KB: Whh tiles
    __shared__ short8 alds[KSR_ * 64];          // 10 KB: own-layer h state
    __shared__ short8 a0lds[KSR_ * 64];         // 10 KB: h0[t] (layer 1 only)
    __shared__ int lcnt;                        // monotonic publish counter

    const int tid = threadIdx.x;
    const int wave = tid >> 6, lane = tid & 63;
    const int layer = (int)(blockIdx.x >> 7);
    const int lb = blockIdx.x & 127;
    const int g = lb & 15, member = lb >> 4;
    const int rawwt = member * WPB_ + wave;      // 0..79
    const bool act = rawwt < NT_;
    const int wtile = act ? rawwt : NT_ - 1;
    const int m = lane & 15, oct = lane >> 4;

    {   // one-time: weights -> LDS; zero own-state buffer (h[-1] = 0); lcnt=0
        const short8* wsrc = (layer ? wr1 : wr0) + (size_t)member * (WPB_ * KSR_ * 64);
        for (int i = tid; i < WPB_ * KSR_ * 64; i += 640) wlds[i] = wsrc[i];
        short8 z = {0, 0, 0, 0, 0, 0, 0, 0};
        if (tid < KSR_ * 64) alds[tid] = z;
        if (tid == 0) lcnt = 0;
    }
    short8 wxv;
    if (layer == 0) wxv = wg0[(size_t)wtile * 64 + lane];
    const float* bp = layer ? b1p : b0p;
    const f32x4 b4 = *(const f32x4*)&bp[wtile * 16 + oct * 4];

    unsigned short* r0g = ring0 + (size_t)g * (RS0_ * 5120);
    unsigned short* r1g = ring1 + (size_t)g * (2 * 5120);
    int* c0 = cnt + g * 16;
    int* c1 = cnt + 1024 + g * 16;
    int* cown = layer ? c1 : c0;

    const int jj = wtile * 4 + oct;
    const int fragaddr = (((jj >> 5) * 64 + ((jj >> 3) & 3) * 16 + m) << 3) + (jj & 7);
    unsigned short* houtp = h1rm + ((size_t)(g * 16 + m) * T_) * HP_ + jj;
    const float* xrow = x + ((size_t)(g * 16 + m) * T_) * IN_ + (oct & 1) * 8;
    const short8* xq = wg1 + (size_t)wtile * (KSR_ * 64) + lane;
    const short8* wl = &wlds[wave * (KSR_ * 64) + lane];
    const short8* al = &alds[lane];
    const short8* a0l = &a0lds[lane];
    const short8 z8 = {0, 0, 0, 0, 0, 0, 0, 0};

    __syncthreads();   // wlds/alds/lcnt ready

    float c = 0.f;

    #pragma unroll 1
    for (int t = 0; t < T_; ++t) {
        f32x4 accC = {0.f, 0.f, 0.f, 0.f}, accD = {0.f, 0.f, 0.f, 0.f};

        if (layer == 0) {
            // x contribution (independent of recurrence, pre-poll)
            const float* xr = xrow + (size_t)t * IN_;
            f32x4 xf0 = *(const f32x4*)xr;
            f32x4 xf1 = *(const f32x4*)(xr + 4);
            S8U xu;
            xu.u[0] = (uint32)f2bf(xf0[0]) | ((uint32)f2bf(xf0[1]) << 16);
            xu.u[1] = (uint32)f2bf(xf0[2]) | ((uint32)f2bf(xf0[3]) << 16);
            xu.u[2] = (uint32)f2bf(xf1[0]) | ((uint32)f2bf(xf1[1]) << 16);
            xu.u[3] = (uint32)f2bf(xf1[2]) | ((uint32)f2bf(xf1[3]) << 16);
            short8 xa = (oct < 2) ? xu.s : z8;
            MF(wxv, xa, accC);

            if (t > 0) {
                // need: all members published h0[t-1]; L1 consumed h0[t-8]
                if (tid == 0) poll2(c0, c1, MEMB_ * t, MEMB_ * (t - 7));
                __syncthreads();
                const unsigned short* sp = r0g + (size_t)((t - 1) & (RS0_ - 1)) * 5120
                                         + wave * 512 + lane * 8;
                short8 v = ld16c(sp);
                vm0();
                alds[wave * 64 + lane] = v;
                __syncthreads();
            }
        } else {
            // ---- gate 1 (usually open: L0 runs ~8 slots ahead): h0[t] ready
            if (tid == 0) poll1(c0, MEMB_ * (t + 1));
            __syncthreads();
            {
                const unsigned short* sp0 = r0g + (size_t)(t & (RS0_ - 1)) * 5120
                                          + wave * 512 + lane * 8;
                short8 v0 = ld16c(sp0);
                vm0();
                a0lds[wave * 64 + lane] = v0;
            }
            __syncthreads();
            // Wih1 @ h0[t] -- independent of h1[t-1]; overlaps c1 propagation
            #pragma unroll
            for (int s = 0; s < KSR_; s += 2) {
                MF(xq[s * 64],       a0l[s * 64],       accC);
                MF(xq[(s + 1) * 64], a0l[(s + 1) * 64], accD);
            }
            // ---- gate 2 (binding): own members published h1[t-1]
            if (t > 0) {
                if (tid == 0) poll1(c1, MEMB_ * t);
                __syncthreads();
                const unsigned short* sp1 = r1g + (size_t)((t - 1) & 1) * 5120
                                          + wave * 512 + lane * 8;
                short8 v1 = ld16c(sp1);
                vm0();
                alds[wave * 64 + lane] = v1;
                __syncthreads();
            }
        }

        // recurrent part: Whh @ h[t-1] from LDS
        f32x4 accA = {0.f, 0.f, 0.f, 0.f}, accB = {0.f, 0.f, 0.f, 0.f};
        #pragma unroll
        for (int s = 0; s < KSR_; s += 2) {
            MF(wl[s * 64],       al[s * 64],       accA);
            MF(wl[(s + 1) * 64], al[(s + 1) * 64], accB);
        }

        float gi = sigm(accA[0] + accB[0] + accC[0] + accD[0] + b4[0]);
        float gf = sigm(accA[1] + accB[1] + accC[1] + accD[1] + b4[1]);
        float gg = tanh_f(accA[2] + accB[2] + accC[2] + accD[2] + b4[2]);
        float go = sigm(accA[3] + accB[3] + accC[3] + accD[3] + b4[3]);
        float cn = gf * c + gi * gg;
        c = cn;
        unsigned short hb = f2bf(go * tanh_f(cn));
        if (act) {
            if (layer == 0) {
                st2c(r0g + (size_t)(t & (RS0_ - 1)) * 5120 + fragaddr, hb);
            } else {
                st2c(r1g + (size_t)(t & 1) * 5120 + fragaddr, hb);
            }
        }
        vm0();   // ring store at IF$ before counting this wave as done
        if (lane == 0) {
            int old = atomicAdd(&lcnt, 1);         // LDS, monotonic
            if (old == WPB_ * (t + 1) - 1)         // last wave of this step
                atomic_inc_cg(cown);
        }
        // h1 row-major store for the head: no intra-kernel consumer -> issue
        // AFTER publish so its ack never sits on the critical path.
        if (act && layer == 1) houtp[(size_t)t * HP_] = hb;
    }
}

// ---------------------------------------------------------------------------
// MLP head: W1/W2/W3 staged in LDS (broadcast reads), one thread per position.
// ---------------------------------------------------------------------------
__global__ __launch_bounds__(256) void head_kernel(
    const unsigned short* __restrict__ h1,
    const float* __restrict__ W1, const float* __restrict__ b1,
    const float* __restrict__ W2, const float* __restrict__ b2,
    const float* __restrict__ W3, const float* __restrict__ b3,
    float* __restrict__ out)
{
    __shared__ float w1s[9000];     // 30x300
    __shared__ float w2s[3200];     // 100x32 (padded)
    __shared__ float w3s[100];
    __shared__ float b1s[30];
    __shared__ float b2s[100];
    const int tid = threadIdx.x;
    for (int i = tid; i < 9000; i += 256) w1s[i] = W1[i];
    for (int i = tid; i < 3000; i += 256) w2s[(i / 30) * 32 + (i % 30)] = W2[i];
    if (tid < 100) { w3s[tid] = W3[tid]; b2s[tid] = b2[tid]; }
    if (tid < 30)  b1s[tid] = b1[tid];
    __syncthreads();

    const int pos = blockIdx.x * 256 + tid;
    const unsigned short* hr = h1 + (size_t)pos * HP_;
    float t1[30];
    #pragma unroll
    for (int j = 0; j < 30; ++j) t1[j] = b1s[j];
    for (int kc = 0; kc < H_; kc += 4) {
        uint32 u0 = *(const uint32*)(hr + kc);
        uint32 u1 = *(const uint32*)(hr + kc + 2);
        float h0v = bf2f((unsigned short)(u0 & 0xffffu));
        float h1v = bf2f((unsigned short)(u0 >> 16));
        float h2v = bf2f((unsigned short)(u1 & 0xffffu));
        float h3v = bf2f((unsigned short)(u1 >> 16));
        #pragma unroll
        for (int j = 0; j < 30; ++j) {
            const f32x4 wv = *(const f32x4*)&w1s[j * H_ + kc];
            t1[j] += h0v * wv[0] + h1v * wv[1] + h2v * wv[2] + h3v * wv[3];
        }
    }
    #pragma unroll
    for (int j = 0; j < 30; ++j) t1[j] = tanh_f(t1[j]);
    float oacc = b3[0];
    for (int j2 = 0; j2 < 100; ++j2) {
        float a2 = b2s[j2];
        #pragma unroll
        for (int k = 0; k < 30; ++k) a2 += t1[k] * w2s[j2 * 32 + k];
        oacc += tanh_f(a2) * w3s[j2];
    }
    out[pos] = sigm(oacc);
}

// ---------------------------------------------------------------------------
extern "C" void kernel_launch(void* const* d_in, const int* in_sizes, int n_in,
                              void* d_out, int out_size, void* d_ws, size_t ws_size,
                              hipStream_t stream)
{
    const float* x    = (const float*)d_in[0];
    const float* Wih0 = (const float*)d_in[1];
    const float* Whh0 = (const float*)d_in[2];
    const float* bih0 = (const float*)d_in[3];
    const float* bhh0 = (const float*)d_in[4];
    const float* Wih1 = (const float*)d_in[5];
    const float* Whh1 = (const float*)d_in[6];
    const float* bih1 = (const float*)d_in[7];
    const float* bhh1 = (const float*)d_in[8];
    const float* W1   = (const float*)d_in[9];
    const float* b1   = (const float*)d_in[10];
    const float* W2   = (const float*)d_in[11];
    const float* b2   = (const float*)d_in[12];
    const float* W3   = (const float*)d_in[13];
    const float* b3   = (const float*)d_in[14];

    // buffers sized for 80 tiles so member-7 blocks can bulk-copy safely
    char* ws = (char*)d_ws;
    const size_t OFF_WR0 = 0x000000;   // 819200 B
    const size_t OFF_WG0 = 0x0D0000;   // 81920 B
    const size_t OFF_WR1 = 0x0E8000;   // 819200 B
    const size_t OFF_WG1 = 0x1B0000;   // 819200 B
    const size_t OFF_B0  = 0x280000;   // 4800 B
    const size_t OFF_B1  = 0x282000;   // 4800 B
    const size_t OFF_CNT = 0x284000;   // c0 @ +0 (1KB), c1 @ +4KB (1KB)
    const size_t OFF_RG0 = 0x290000;   // 16 x 8 x 10240 B = 1310720
    const size_t OFF_RG1 = 0x3D0000;   // 16 x 2 x 10240 B = 327680
    const size_t OFF_H1  = 0x420000;   // 41,943,040 B
    const size_t HB      = (size_t)B_ * T_ * HP_ * 2;
    const size_t NEED    = OFF_H1 + HB;          // ~46 MB
    if (ws_size < NEED) return;

    uint32* wr0 = (uint32*)(ws + OFF_WR0);
    uint32* wg0 = (uint32*)(ws + OFF_WG0);
    uint32* wr1 = (uint32*)(ws + OFF_WR1);
    uint32* wg1 = (uint32*)(ws + OFF_WG1);
    float*  b0p = (float*)(ws + OFF_B0);
    float*  b1p = (float*)(ws + OFF_B1);
    int*    cnt = (int*)(ws + OFF_CNT);
    unsigned short* rg0 = (unsigned short*)(ws + OFF_RG0);
    unsigned short* rg1 = (unsigned short*)(ws + OFF_RG1);
    unsigned short* h1b = (unsigned short*)(ws + OFF_H1);

    hipMemsetAsync(ws + OFF_CNT, 0, 8192, stream);   // counters -> epoch 0

    hipLaunchKernelGGL(pack_kernel, dim3(591), dim3(256), 0, stream,
                       Wih0, Whh0, bih0, bhh0, Wih1, Whh1, bih1, bhh1,
                       wr0, wg0, wr1, wg1, b0p, b1p);
    hipLaunchKernelGGL(lstm_dual, dim3(256), dim3(640), 0, stream,
                       x, (const short8*)wr0, (const short8*)wg0,
                       (const short8*)wr1, (const short8*)wg1,
                       b0p, b1p, h1b, rg0, rg1, cnt);
    hipLaunchKernelGGL(head_kernel, dim3(256), dim3(256), 0, stream,
                       h1b, W1, b1, W2, b2, W3, b3, (float*)d_out);
}